// Round 16
// baseline (493.029 us; speedup 1.0000x reference)
//
#include <hip/hip_runtime.h>

#define BB 4
#define SS 2048
#define DDIM 512
#define HH 8
#define MTOK (BB*SS)   // 8192
#define BHN (BB*HH)    // 32

typedef _Float16 f16;
typedef __attribute__((ext_vector_type(8))) _Float16 half8;
typedef __attribute__((ext_vector_type(4))) _Float16 half4;
typedef __attribute__((ext_vector_type(4))) float float4v;
typedef __attribute__((ext_vector_type(4))) int int4v;

#define SCALE_L2E 0.180336880073616f   // 0.125 * log2(e)
#define L2E 1.44269504088896f
#define EBIAS 4.0f                     // cancels in softmax; f16 overflow headroom
#define MASKVAL -65504.0f              // f16 -max; exp2 -> 0

__device__ __forceinline__ float4v mfma_k32(half8 a, half8 b, float4v c) {
  return __builtin_amdgcn_mfma_f32_16x16x32_f16(a, b, c, 0, 0, 0);
}

__device__ __forceinline__ half8 cvt8(float4v a, float4v b) {
  half8 r;
  r[0] = (f16)a[0]; r[1] = (f16)a[1]; r[2] = (f16)a[2]; r[3] = (f16)a[3];
  r[4] = (f16)b[0]; r[5] = (f16)b[1]; r[6] = (f16)b[2]; r[7] = (f16)b[3];
  return r;
}

// ---------------- mask dtype detection ----------------
__global__ __launch_bounds__(256) void detect_mask_kernel(
    const unsigned int* __restrict__ m, unsigned int* __restrict__ flag) {
  unsigned int v = 0;
  const int base = blockIdx.x * 1024;
  for (int j = threadIdx.x; j < 1024; j += 256)
    if (m[base + j] > 1u) v = 1u;
  if (v) atomicOr(flag, 1u);
}

// ---------------- batched QKV projection ----------------
// z=0: Qp [tok][512] f16
// z=1: Kfrag[bh][tok>>4][dk>>5][(tok&15)+16*((dk>>3)&3)][dk&7]  (A-frag order)
// z=2: Vfrag[bh][tok>>5][dv>>4][(dv&15)+16*((tok>>2)&3)][((tok>>2)&4)+(tok&3)]
__global__ __launch_bounds__(256) void gemm_qkv(
    const float* __restrict__ inQ, const float* __restrict__ inK,
    const float* __restrict__ inV, const float* __restrict__ WQ,
    const float* __restrict__ WK, const float* __restrict__ WV,
    f16* __restrict__ Qp, f16* __restrict__ Kfrag, f16* __restrict__ Vfrag) {
  __shared__ f16 As[128][40];
  __shared__ f16 Bs[128][40];
  const int z = blockIdx.z;
  const float* A = (z == 0) ? inQ : (z == 1) ? inK : inV;
  const float* W = (z == 0) ? WQ : (z == 1) ? WK : WV;
  const int t = threadIdx.x;
  const int bm = blockIdx.x * 128;
  const int bn = blockIdx.y * 128;
  const int w = t >> 6, ln = t & 63;
  const int wr = w >> 1, wc = w & 1;
  const int lr = ln & 15, lg = ln >> 4;
  const int srow = t >> 1, scol = (t & 1) * 16;

  float4v acc[4][4] = {};

  for (int k0 = 0; k0 < 512; k0 += 32) {
    {
      const float* ap = A + (size_t)(bm + srow) * 512 + k0 + scol;
      float4v x0 = *(const float4v*)ap,       x1 = *(const float4v*)(ap + 4);
      float4v x2 = *(const float4v*)(ap + 8), x3 = *(const float4v*)(ap + 12);
      *(half8*)&As[srow][scol]     = cvt8(x0, x1);
      *(half8*)&As[srow][scol + 8] = cvt8(x2, x3);
    }
    {
      const float* wp = W + (size_t)(bn + srow) * 512 + k0 + scol;
      float4v x0 = *(const float4v*)wp,       x1 = *(const float4v*)(wp + 4);
      float4v x2 = *(const float4v*)(wp + 8), x3 = *(const float4v*)(wp + 12);
      *(half8*)&Bs[srow][scol]     = cvt8(x0, x1);
      *(half8*)&Bs[srow][scol + 8] = cvt8(x2, x3);
    }
    __syncthreads();
    half8 af[4], bf[4];
    #pragma unroll
    for (int m = 0; m < 4; m++) af[m] = *(const half8*)&As[wr * 64 + m * 16 + lr][lg * 8];
    #pragma unroll
    for (int n = 0; n < 4; n++) bf[n] = *(const half8*)&Bs[wc * 64 + n * 16 + lr][lg * 8];
    #pragma unroll
    for (int m = 0; m < 4; m++)
      #pragma unroll
      for (int n = 0; n < 4; n++) acc[m][n] = mfma_k32(af[m], bf[n], acc[m][n]);
    __syncthreads();
  }

  #pragma unroll
  for (int m = 0; m < 4; m++) {
    int row = bm + wr * 64 + m * 16 + lg * 4;
    #pragma unroll
    for (int n = 0; n < 4; n++) {
      int col = bn + wc * 64 + n * 16 + lr;
      int b_ = row >> 11, s_ = row & 2047, h_ = col >> 6, d_ = col & 63;
      if (z == 0) {
        #pragma unroll
        for (int r = 0; r < 4; r++)
          Qp[(size_t)(row + r) * 512 + col] = (f16)acc[m][n][r];
      } else if (z == 1) {
        #pragma unroll
        for (int r = 0; r < 4; r++) {
          int tok = s_ + r;
          Kfrag[((((size_t)(b_ * 8 + h_)) * 128 + (tok >> 4)) * 2 + (d_ >> 5)) * 512 +
                ((tok & 15) + 16 * ((d_ >> 3) & 3)) * 8 + (d_ & 7)] =
              (f16)acc[m][n][r];
        }
      } else {
        half4 ph;
        ph[0] = (f16)acc[m][n][0]; ph[1] = (f16)acc[m][n][1];
        ph[2] = (f16)acc[m][n][2]; ph[3] = (f16)acc[m][n][3];
        *(half4*)&Vfrag[((((size_t)(b_ * 8 + h_)) * 64 + (s_ >> 5)) * 4 + (d_ >> 4)) * 512 +
                        ((d_ & 15) + 16 * ((s_ >> 2) & 3)) * 8 + ((s_ >> 2) & 4)] = ph;
      }
    }
  }
}

// ---------------- output GEMM: ctx (f16) x W_fc^T -> fp32 ----------------
__global__ __launch_bounds__(256) void gemm_out(const f16* __restrict__ ctx,
                                                const float* __restrict__ W,
                                                float* __restrict__ Out) {
  __shared__ f16 As[128][40];
  __shared__ f16 Bs[128][40];
  const int t = threadIdx.x;
  const int bm = blockIdx.x * 128;
  const int bn = blockIdx.y * 128;
  const int w = t >> 6, ln = t & 63;
  const int wr = w >> 1, wc = w & 1;
  const int lr = ln & 15, lg = ln >> 4;
  const int srow = t >> 1, scol = (t & 1) * 16;

  float4v acc[4][4] = {};

  for (int k0 = 0; k0 < 512; k0 += 32) {
    {
      const f16* ap = ctx + (size_t)(bm + srow) * 512 + k0 + scol;
      *(half8*)&As[srow][scol]     = *(const half8*)(ap);
      *(half8*)&As[srow][scol + 8] = *(const half8*)(ap + 8);
    }
    {
      const float* wp = W + (size_t)(bn + srow) * 512 + k0 + scol;
      float4v x0 = *(const float4v*)wp,       x1 = *(const float4v*)(wp + 4);
      float4v x2 = *(const float4v*)(wp + 8), x3 = *(const float4v*)(wp + 12);
      *(half8*)&Bs[srow][scol]     = cvt8(x0, x1);
      *(half8*)&Bs[srow][scol + 8] = cvt8(x2, x3);
    }
    __syncthreads();
    half8 af[4], bf[4];
    #pragma unroll
    for (int m = 0; m < 4; m++) af[m] = *(const half8*)&As[wr * 64 + m * 16 + lr][lg * 8];
    #pragma unroll
    for (int n = 0; n < 4; n++) bf[n] = *(const half8*)&Bs[wc * 64 + n * 16 + lr][lg * 8];
    #pragma unroll
    for (int m = 0; m < 4; m++)
      #pragma unroll
      for (int n = 0; n < 4; n++) acc[m][n] = mfma_k32(af[m], bf[n], acc[m][n]);
    __syncthreads();
  }

  #pragma unroll
  for (int m = 0; m < 4; m++) {
    int row = bm + wr * 64 + m * 16 + lg * 4;
    #pragma unroll
    for (int n = 0; n < 4; n++) {
      int col = bn + wc * 64 + n * 16 + lr;
      #pragma unroll
      for (int r = 0; r < 4; r++)
        Out[(size_t)(row + r) * 512 + col] = acc[m][n][r];
    }
  }
}

// ---------------- fused attention: block = ONE head, E forced live ----------------
// Block = (b, h, 16 q-rows), 512 thr = 8 waves; wave w owns k-slice
// [w*256, w*256+256) -> E = 8 half8 = 32 VGPRs that MUST stay live from
// compute to normalize+store (allocator can't collapse below ~110 VGPR ->
// with __launch_bounds__(512,4) budget=128 it finally keeps a real load
// pipeline; r12-r15's 64-VGPR serialization is structurally impossible).
// ONE barrier per block (vs 16 in r11); 8-wave barrier group; 2 blocks/CU.
// Single QK^T + single exp.  bias+mask preloaded to 8 half8 regs (read once).
// Grid 4096 = qt*32 + bh: each XCD keeps 4 (b,h) K/V slices (2 MB) L2-hot.
#define LOADT(dst, base, st) {                                  \
    const f16* p_ = (base) + (size_t)(st) * 2048;               \
    dst##0 = *(const half8*)(p_);                               \
    dst##1 = *(const half8*)(p_ + 512);                         \
    dst##2 = *(const half8*)(p_ + 1024);                        \
    dst##3 = *(const half8*)(p_ + 1536); }

__global__ __launch_bounds__(512, 4) void attn_fused(
    const f16* __restrict__ Qp, const f16* __restrict__ Kfrag,
    const f16* __restrict__ Vfrag, const float* __restrict__ other,
    const unsigned char* __restrict__ mask8, const int* __restrict__ mask32,
    const unsigned int* __restrict__ flag, float* __restrict__ attn_out,
    f16* __restrict__ ctx) {
  __shared__ float red[8][16];       // [wave][q] row-sum partials
  __shared__ float red2[8][16][66];  // [wave][q][dv] PV partials (33.8 KB)

  const int t = threadIdx.x;
  const int bid = blockIdx.x;
  const int bh = bid & 31;           // b*8+h; bh%8 stable per XCD
  const int qblk = (bid >> 5) * 16;
  const int b = bh >> 3, h = bh & 7;
  const int w = t >> 6, ln = t & 63;
  const int lr = ln & 15, lg = ln >> 4;
  const bool use8 = (*flag) != 0;

  const int q_g = qblk + lr;
  const f16* kfb = Kfrag + (size_t)bh * 131072 + ln * 8;
  const f16* vfb = Vfrag + (size_t)bh * 131072 + ln * 8;

  // Q fragment (this block's single head)
  const f16* qpp = Qp + ((size_t)b * SS + q_g) * 512 + h * 64 + lg * 8;
  const half8 qf0 = *(const half8*)(qpp);
  const half8 qf1 = *(const half8*)(qpp + 32);

  // ---- preload this lane's 64 bias values (masked, log2e-scaled, f16) ----
  half8 o0, o1, o2, o3, o4, o5, o6, o7;
  #define OLOAD(dst, g) {                                                 \
    const size_t ob_ = ((size_t)b * SS + q_g) * SS + w * 256 + (g) * 32 + lg * 4; \
    float4v x0 = *(const float4v*)&other[ob_];                            \
    float4v x1 = *(const float4v*)&other[ob_ + 16];                       \
    float4v r0, r1;                                                       \
    if (use8) {                                                           \
      unsigned int m0 = *(const unsigned int*)&mask8[ob_];                \
      unsigned int m1 = *(const unsigned int*)&mask8[ob_ + 16];           \
      _Pragma("unroll")                                                   \
      for (int r = 0; r < 4; r++) {                                       \
        r0[r] = ((m0 >> (8 * r)) & 0xffu) ? MASKVAL : fmaf(x0[r], L2E, -EBIAS); \
        r1[r] = ((m1 >> (8 * r)) & 0xffu) ? MASKVAL : fmaf(x1[r], L2E, -EBIAS); \
      }                                                                   \
    } else {                                                              \
      int4v m0 = *(const int4v*)&mask32[ob_];                             \
      int4v m1 = *(const int4v*)&mask32[ob_ + 16];                        \
      _Pragma("unroll")                                                   \
      for (int r = 0; r < 4; r++) {                                       \
        r0[r] = m0[r] ? MASKVAL : fmaf(x0[r], L2E, -EBIAS);               \
        r1[r] = m1[r] ? MASKVAL : fmaf(x1[r], L2E, -EBIAS);               \
      }                                                                   \
    }                                                                     \
    dst = cvt8(r0, r1);                                                   \
  }
  OLOAD(o0, 0); OLOAD(o1, 1); OLOAD(o2, 2); OLOAD(o3, 3);
  OLOAD(o4, 4); OLOAD(o5, 5); OLOAD(o6, 6); OLOAD(o7, 7);
  #undef OLOAD

  half8 kA0, kA1, kA2, kA3, kB0, kB1, kB2, kB3;
  half8 vf0, vf1, vf2, vf3;
  half8 e0, e1, e2, e3, e4, e5, e6, e7;
  float rs = 0.f;
  float4v cacc0 = {}, cacc1 = {}, cacc2 = {}, cacc3 = {};

  #define BODY(kf, oreg, edst) {                                          \
    float4v s0 = {}, s1 = {};                                             \
    s0 = mfma_k32(kf##0, qf0, s0);                                        \
    s0 = mfma_k32(kf##1, qf1, s0);                                        \
    s1 = mfma_k32(kf##2, qf0, s1);                                        \
    s1 = mfma_k32(kf##3, qf1, s1);                                        \
    float4v ev0, ev1;                                                     \
    _Pragma("unroll")                                                     \
    for (int r = 0; r < 4; r++) {                                         \
      ev0[r] = exp2f(fmaf(s0[r], SCALE_L2E, (float)oreg[r]));             \
      ev1[r] = exp2f(fmaf(s1[r], SCALE_L2E, (float)oreg[4 + r]));         \
    }                                                                     \
    rs += (ev0[0] + ev0[1]) + (ev0[2] + ev0[3]) +                         \
          (ev1[0] + ev1[1]) + (ev1[2] + ev1[3]);                          \
    edst = cvt8(ev0, ev1);                                                \
    cacc0 = mfma_k32(edst, vf0, cacc0);                                   \
    cacc1 = mfma_k32(edst, vf1, cacc1);                                   \
    cacc2 = mfma_k32(edst, vf2, cacc2);                                   \
    cacc3 = mfma_k32(edst, vf3, cacc3);                                   \
  }

  const int s0i = w * 8;
  LOADT(kA, kfb, s0i + 0);
  LOADT(vf, vfb, s0i + 0);

  LOADT(kB, kfb, s0i + 1);
  BODY(kA, o0, e0);
  LOADT(vf, vfb, s0i + 1);
  LOADT(kA, kfb, s0i + 2);
  BODY(kB, o1, e1);
  LOADT(vf, vfb, s0i + 2);
  LOADT(kB, kfb, s0i + 3);
  BODY(kA, o2, e2);
  LOADT(vf, vfb, s0i + 3);
  LOADT(kA, kfb, s0i + 4);
  BODY(kB, o3, e3);
  LOADT(vf, vfb, s0i + 4);
  LOADT(kB, kfb, s0i + 5);
  BODY(kA, o4, e4);
  LOADT(vf, vfb, s0i + 5);
  LOADT(kA, kfb, s0i + 6);
  BODY(kB, o5, e5);
  LOADT(vf, vfb, s0i + 6);
  LOADT(kB, kfb, s0i + 7);
  BODY(kA, o6, e6);
  LOADT(vf, vfb, s0i + 7);
  BODY(kB, o7, e7);
  #undef BODY

  // ---- cross-wave reductions (ONE barrier total) ----
  {
    float v = rs;
    v += __shfl_xor(v, 16);
    v += __shfl_xor(v, 32);
    if (ln < 16) red[w][lr] = v;
  }
  #pragma unroll
  for (int r = 0; r < 4; r++) {
    red2[w][lg * 4 + r][0 * 16 + lr] = cacc0[r];
    red2[w][lg * 4 + r][1 * 16 + lr] = cacc1[r];
    red2[w][lg * 4 + r][2 * 16 + lr] = cacc2[r];
    red2[w][lg * 4 + r][3 * 16 + lr] = cacc3[r];
  }
  __syncthreads();

  float lsum = 0.f;
  #pragma unroll
  for (int ww = 0; ww < 8; ww++) lsum += red[ww][lr];
  const float invl = 1.0f / lsum;

  float* abase = attn_out + ((size_t)bh * SS + q_g) * SS + w * 256;
  #define ASTORE(e, g) {                                                  \
    float4v av0, av1;                                                     \
    av0[0] = (float)e[0] * invl; av0[1] = (float)e[1] * invl;             \
    av0[2] = (float)e[2] * invl; av0[3] = (float)e[3] * invl;             \
    av1[0] = (float)e[4] * invl; av1[1] = (float)e[5] * invl;             \
    av1[2] = (float)e[6] * invl; av1[3] = (float)e[7] * invl;             \
    *(float4v*)(abase + (g) * 32 + lg * 4) = av0;                         \
    *(float4v*)(abase + (g) * 32 + 16 + lg * 4) = av1;                    \
  }
  ASTORE(e0, 0); ASTORE(e1, 1); ASTORE(e2, 2); ASTORE(e3, 3);
  ASTORE(e4, 4); ASTORE(e5, 5); ASTORE(e6, 6); ASTORE(e7, 7);
  #undef ASTORE

  // ---- ctx: sum 8 wave-partials, normalize, store ----
  {
    const int q = t >> 5;           // 0..15
    const int dv0 = (t & 31) * 2;   // 0..62
    float l_c = 0.f, c0 = 0.f, c1 = 0.f;
    #pragma unroll
    for (int ww = 0; ww < 8; ww++) {
      l_c += red[ww][q];
      c0 += red2[ww][q][dv0];
      c1 += red2[ww][q][dv0 + 1];
    }
    const float invc = 1.0f / l_c;
    f16* cp = ctx + ((size_t)b * SS + qblk + q) * 512 + h * 64 + dv0;
    cp[0] = (f16)(c0 * invc);
    cp[1] = (f16)(c1 * invc);
  }
}

extern "C" void kernel_launch(void* const* d_in, const int* in_sizes, int n_in,
                              void* d_out, int out_size, void* d_ws, size_t ws_size,
                              hipStream_t stream) {
  const float* inQ   = (const float*)d_in[0];
  const float* inK   = (const float*)d_in[1];
  const float* inV   = (const float*)d_in[2];
  const void*  mask  = d_in[3];
  const float* other = (const float*)d_in[4];
  const float* WQ    = (const float*)d_in[5];
  const float* WK    = (const float*)d_in[6];
  const float* WV    = (const float*)d_in[7];
  const float* WF    = (const float*)d_in[8];

  char* ws = (char*)d_ws;
  size_t off = 0;
  unsigned int* flag = (unsigned int*)(ws + off); off += 256;
  f16* Qp    = (f16*)(ws + off); off += (size_t)MTOK * 512 * 2;
  f16* Kfrag = (f16*)(ws + off); off += (size_t)MTOK * 512 * 2;
  f16* Vfrag = (f16*)(ws + off); off += (size_t)MTOK * 512 * 2;
  f16* ctx   = (f16*)(ws + off); off += (size_t)MTOK * 512 * 2;
  if (ws_size < off) return;

  float* outp  = (float*)d_out;
  float* attnp = outp + (size_t)MTOK * DDIM;

  hipMemsetAsync(flag, 0, 256, stream);
  detect_mask_kernel<<<64, 256, 0, stream>>>((const unsigned int*)mask, flag);

  gemm_qkv<<<dim3(64, 4, 3), 256, 0, stream>>>(inQ, inK, inV, WQ, WK, WV,
                                               Qp, Kfrag, Vfrag);

  attn_fused<<<4096, 512, 0, stream>>>(
      Qp, Kfrag, Vfrag, other, (const unsigned char*)mask, (const int*)mask,
      flag, attnp, ctx);

  gemm_out<<<dim3(64, 4), 256, 0, stream>>>(ctx, WF, outp);
}

// Round 17
// 361.125 us; speedup vs baseline: 1.3653x; 1.3653x over previous
//
#include <hip/hip_runtime.h>

#define BB 4
#define SS 2048
#define DDIM 512
#define HH 8
#define MTOK (BB*SS)   // 8192
#define BHN (BB*HH)    // 32

typedef _Float16 f16;
typedef __attribute__((ext_vector_type(8))) _Float16 half8;
typedef __attribute__((ext_vector_type(4))) _Float16 half4;
typedef __attribute__((ext_vector_type(2))) _Float16 half2v;
typedef __attribute__((ext_vector_type(4))) float float4v;
typedef __attribute__((ext_vector_type(4))) int int4v;

#define SCALE_L2E 0.180336880073616f   // 0.125 * log2(e)
#define L2E 1.44269504088896f
#define EBIAS 4.0f                     // cancels in softmax; f16 overflow headroom
#define MASKVAL -65504.0f              // f16 -max; exp2 -> 0

__device__ __forceinline__ float4v mfma_k32(half8 a, half8 b, float4v c) {
  return __builtin_amdgcn_mfma_f32_16x16x32_f16(a, b, c, 0, 0, 0);
}

__device__ __forceinline__ half8 cvt8(float4v a, float4v b) {
  half8 r;
  r[0] = (f16)a[0]; r[1] = (f16)a[1]; r[2] = (f16)a[2]; r[3] = (f16)a[3];
  r[4] = (f16)b[0]; r[5] = (f16)b[1]; r[6] = (f16)b[2]; r[7] = (f16)b[3];
  return r;
}

// ---------------- mask dtype detection ----------------
__global__ __launch_bounds__(256) void detect_mask_kernel(
    const unsigned int* __restrict__ m, unsigned int* __restrict__ flag) {
  unsigned int v = 0;
  const int base = blockIdx.x * 1024;
  for (int j = threadIdx.x; j < 1024; j += 256)
    if (m[base + j] > 1u) v = 1u;
  if (v) atomicOr(flag, 1u);
}

// ---------------- batched QKV projection ----------------
// z=0: Qp [tok][512] f16
// z=1: Kfrag[bh][tok>>4][dk>>5][(tok&15)+16*((dk>>3)&3)][dk&7]  (A-frag order)
// z=2: Vfrag[bh][tok>>5][dv>>4][(dv&15)+16*((tok>>2)&3)][((tok>>2)&4)+(tok&3)]
__global__ __launch_bounds__(256) void gemm_qkv(
    const float* __restrict__ inQ, const float* __restrict__ inK,
    const float* __restrict__ inV, const float* __restrict__ WQ,
    const float* __restrict__ WK, const float* __restrict__ WV,
    f16* __restrict__ Qp, f16* __restrict__ Kfrag, f16* __restrict__ Vfrag) {
  __shared__ f16 As[128][40];
  __shared__ f16 Bs[128][40];
  const int z = blockIdx.z;
  const float* A = (z == 0) ? inQ : (z == 1) ? inK : inV;
  const float* W = (z == 0) ? WQ : (z == 1) ? WK : WV;
  const int t = threadIdx.x;
  const int bm = blockIdx.x * 128;
  const int bn = blockIdx.y * 128;
  const int w = t >> 6, ln = t & 63;
  const int wr = w >> 1, wc = w & 1;
  const int lr = ln & 15, lg = ln >> 4;
  const int srow = t >> 1, scol = (t & 1) * 16;

  float4v acc[4][4] = {};

  for (int k0 = 0; k0 < 512; k0 += 32) {
    {
      const float* ap = A + (size_t)(bm + srow) * 512 + k0 + scol;
      float4v x0 = *(const float4v*)ap,       x1 = *(const float4v*)(ap + 4);
      float4v x2 = *(const float4v*)(ap + 8), x3 = *(const float4v*)(ap + 12);
      *(half8*)&As[srow][scol]     = cvt8(x0, x1);
      *(half8*)&As[srow][scol + 8] = cvt8(x2, x3);
    }
    {
      const float* wp = W + (size_t)(bn + srow) * 512 + k0 + scol;
      float4v x0 = *(const float4v*)wp,       x1 = *(const float4v*)(wp + 4);
      float4v x2 = *(const float4v*)(wp + 8), x3 = *(const float4v*)(wp + 12);
      *(half8*)&Bs[srow][scol]     = cvt8(x0, x1);
      *(half8*)&Bs[srow][scol + 8] = cvt8(x2, x3);
    }
    __syncthreads();
    half8 af[4], bf[4];
    #pragma unroll
    for (int m = 0; m < 4; m++) af[m] = *(const half8*)&As[wr * 64 + m * 16 + lr][lg * 8];
    #pragma unroll
    for (int n = 0; n < 4; n++) bf[n] = *(const half8*)&Bs[wc * 64 + n * 16 + lr][lg * 8];
    #pragma unroll
    for (int m = 0; m < 4; m++)
      #pragma unroll
      for (int n = 0; n < 4; n++) acc[m][n] = mfma_k32(af[m], bf[n], acc[m][n]);
    __syncthreads();
  }

  #pragma unroll
  for (int m = 0; m < 4; m++) {
    int row = bm + wr * 64 + m * 16 + lg * 4;
    #pragma unroll
    for (int n = 0; n < 4; n++) {
      int col = bn + wc * 64 + n * 16 + lr;
      int b_ = row >> 11, s_ = row & 2047, h_ = col >> 6, d_ = col & 63;
      if (z == 0) {
        #pragma unroll
        for (int r = 0; r < 4; r++)
          Qp[(size_t)(row + r) * 512 + col] = (f16)acc[m][n][r];
      } else if (z == 1) {
        #pragma unroll
        for (int r = 0; r < 4; r++) {
          int tok = s_ + r;
          Kfrag[((((size_t)(b_ * 8 + h_)) * 128 + (tok >> 4)) * 2 + (d_ >> 5)) * 512 +
                ((tok & 15) + 16 * ((d_ >> 3) & 3)) * 8 + (d_ & 7)] =
              (f16)acc[m][n][r];
        }
      } else {
        half4 ph;
        ph[0] = (f16)acc[m][n][0]; ph[1] = (f16)acc[m][n][1];
        ph[2] = (f16)acc[m][n][2]; ph[3] = (f16)acc[m][n][3];
        *(half4*)&Vfrag[((((size_t)(b_ * 8 + h_)) * 64 + (s_ >> 5)) * 4 + (d_ >> 4)) * 512 +
                        ((d_ & 15) + 16 * ((s_ >> 2) & 3)) * 8 + ((s_ >> 2) & 4)] = ph;
      }
    }
  }
}

// ---------------- output GEMM: ctx (f16) x W_fc^T -> fp32 ----------------
__global__ __launch_bounds__(256) void gemm_out(const f16* __restrict__ ctx,
                                                const float* __restrict__ W,
                                                float* __restrict__ Out) {
  __shared__ f16 As[128][40];
  __shared__ f16 Bs[128][40];
  const int t = threadIdx.x;
  const int bm = blockIdx.x * 128;
  const int bn = blockIdx.y * 128;
  const int w = t >> 6, ln = t & 63;
  const int wr = w >> 1, wc = w & 1;
  const int lr = ln & 15, lg = ln >> 4;
  const int srow = t >> 1, scol = (t & 1) * 16;

  float4v acc[4][4] = {};

  for (int k0 = 0; k0 < 512; k0 += 32) {
    {
      const f16* ap = ctx + (size_t)(bm + srow) * 512 + k0 + scol;
      *(half8*)&As[srow][scol]     = *(const half8*)(ap);
      *(half8*)&As[srow][scol + 8] = *(const half8*)(ap + 8);
    }
    {
      const float* wp = W + (size_t)(bn + srow) * 512 + k0 + scol;
      float4v x0 = *(const float4v*)wp,       x1 = *(const float4v*)(wp + 4);
      float4v x2 = *(const float4v*)(wp + 8), x3 = *(const float4v*)(wp + 12);
      *(half8*)&Bs[srow][scol]     = cvt8(x0, x1);
      *(half8*)&Bs[srow][scol + 8] = cvt8(x2, x3);
    }
    __syncthreads();
    half8 af[4], bf[4];
    #pragma unroll
    for (int m = 0; m < 4; m++) af[m] = *(const half8*)&As[wr * 64 + m * 16 + lr][lg * 8];
    #pragma unroll
    for (int n = 0; n < 4; n++) bf[n] = *(const half8*)&Bs[wc * 64 + n * 16 + lr][lg * 8];
    #pragma unroll
    for (int m = 0; m < 4; m++)
      #pragma unroll
      for (int n = 0; n < 4; n++) acc[m][n] = mfma_k32(af[m], bf[n], acc[m][n]);
    __syncthreads();
  }

  #pragma unroll
  for (int m = 0; m < 4; m++) {
    int row = bm + wr * 64 + m * 16 + lg * 4;
    #pragma unroll
    for (int n = 0; n < 4; n++) {
      int col = bn + wc * 64 + n * 16 + lr;
      #pragma unroll
      for (int r = 0; r < 4; r++)
        Out[(size_t)(row + r) * 512 + col] = acc[m][n][r];
    }
  }
}

// ---------------- fused attention: r14 structure + double-buffered reduce ----------------
// Block = (b, 16 q-rows), 1024 thr = 16 waves; heads sequential; wave w owns
// k-slice [w*128,w*128+128).  E in registers -> ONE QK^T + ONE exp.
// other+mask staged once (66 KB LDS).  CHANGE vs r14: red/red2 are DOUBLE
// BUFFERED (red2 in f16 so both buffers fit: total LDS 135.4 KB) -> ONE
// barrier per head, and the attn-store burst (131 KB/head) issues after the
// sums are in registers with NO trailing barrier: stores drain under the
// NEXT head's entire compute phase (in-order vmcnt: waits target the older
// K/V loads, not the younger stores).  Barriers 16 -> 8 per block.
#define LOADT(dst, base, st) {                                  \
    const f16* p_ = (base) + (size_t)(st) * 2048;               \
    dst##0 = *(const half8*)(p_);                               \
    dst##1 = *(const half8*)(p_ + 512);                         \
    dst##2 = *(const half8*)(p_ + 1024);                        \
    dst##3 = *(const half8*)(p_ + 1536); }

__global__ __launch_bounds__(1024) void attn_fused(
    const f16* __restrict__ Qp, const f16* __restrict__ Kfrag,
    const f16* __restrict__ Vfrag, const float* __restrict__ other,
    const unsigned char* __restrict__ mask8, const int* __restrict__ mask32,
    const unsigned int* __restrict__ flag, float* __restrict__ attn_out,
    f16* __restrict__ ctx) {
  __shared__ f16 othm[16][2056];        // masked, log2e-scaled f16 (65.8 KB)
  __shared__ float red[2][16][16];      // row-sum partials, dbuf   (2 KB)
  __shared__ f16 red2h[2][16][16][66];  // PV partials f16, dbuf    (67.6 KB)

  const int t = threadIdx.x;
  const int bid = blockIdx.x;
  const int b = bid & 3;
  const int qblk = (bid >> 2) * 16;
  const int w = t >> 6, ln = t & 63;
  const int lr = ln & 15, lg = ln >> 4;
  const bool use8 = (*flag) != 0;

  // ---- stage other+mask once: thread -> (q = t>>6, 32 k at (t&63)*32) ----
  {
    const int q = t >> 6, k0 = (t & 63) * 32;
    const size_t base = ((size_t)b * SS + qblk + q) * SS + k0;
    const float* op = other + base;
    if (use8) {
      const unsigned char* mp = mask8 + base;
      #pragma unroll
      for (int g = 0; g < 4; g++) {
        unsigned int mw0 = *(const unsigned int*)(mp + g * 8);
        unsigned int mw1 = *(const unsigned int*)(mp + g * 8 + 4);
        float4v o0 = *(const float4v*)(op + g * 8);
        float4v o1 = *(const float4v*)(op + g * 8 + 4);
        float4v r0, r1;
        #pragma unroll
        for (int r = 0; r < 4; r++) {
          r0[r] = ((mw0 >> (8 * r)) & 0xffu) ? MASKVAL : fmaf(o0[r], L2E, -EBIAS);
          r1[r] = ((mw1 >> (8 * r)) & 0xffu) ? MASKVAL : fmaf(o1[r], L2E, -EBIAS);
        }
        *(half8*)&othm[q][k0 + g * 8] = cvt8(r0, r1);
      }
    } else {
      const int* mp = mask32 + base;
      #pragma unroll
      for (int g = 0; g < 4; g++) {
        int4v m0 = *(const int4v*)(mp + g * 8);
        int4v m1 = *(const int4v*)(mp + g * 8 + 4);
        float4v o0 = *(const float4v*)(op + g * 8);
        float4v o1 = *(const float4v*)(op + g * 8 + 4);
        float4v r0, r1;
        #pragma unroll
        for (int r = 0; r < 4; r++) {
          r0[r] = m0[r] ? MASKVAL : fmaf(o0[r], L2E, -EBIAS);
          r1[r] = m1[r] ? MASKVAL : fmaf(o1[r], L2E, -EBIAS);
        }
        *(half8*)&othm[q][k0 + g * 8] = cvt8(r0, r1);
      }
    }
  }
  __syncthreads();

  const int q_g = qblk + lr;
  const f16* kfb = Kfrag + (size_t)(b * 8) * 131072 + ln * 8;
  const f16* vfb = Vfrag + (size_t)(b * 8) * 131072 + ln * 8;
  const f16* qpp = Qp + ((size_t)b * SS + q_g) * 512 + lg * 8;

  half8 kA0, kA1, kA2, kA3, kB0, kB1, kB2, kB3;
  half8 vf0, vf1, vf2, vf3;

  LOADT(kA, kfb, w * 4 + 0);

  #define BODY(kf, edst, g) {                                             \
    float4v s0 = {}, s1 = {};                                             \
    s0 = mfma_k32(kf##0, qf0, s0);                                        \
    s0 = mfma_k32(kf##1, qf1, s0);                                        \
    s1 = mfma_k32(kf##2, qf0, s1);                                        \
    s1 = mfma_k32(kf##3, qf1, s1);                                        \
    const int kbase = w * 128 + (g) * 32;                                 \
    const half4 o40 = *(const half4*)&othm[lr][kbase + lg * 4];           \
    const half4 o41 = *(const half4*)&othm[lr][kbase + 16 + lg * 4];      \
    float4v ev0, ev1;                                                     \
    _Pragma("unroll")                                                     \
    for (int r = 0; r < 4; r++) {                                         \
      ev0[r] = exp2f(fmaf(s0[r], SCALE_L2E, (float)o40[r]));              \
      ev1[r] = exp2f(fmaf(s1[r], SCALE_L2E, (float)o41[r]));              \
    }                                                                     \
    rs += (ev0[0] + ev0[1]) + (ev0[2] + ev0[3]) +                         \
          (ev1[0] + ev1[1]) + (ev1[2] + ev1[3]);                          \
    edst = cvt8(ev0, ev1);                                                \
    cacc0 = mfma_k32(edst, vf0, cacc0);                                   \
    cacc1 = mfma_k32(edst, vf1, cacc1);                                   \
    cacc2 = mfma_k32(edst, vf2, cacc2);                                   \
    cacc3 = mfma_k32(edst, vf3, cacc3);                                   \
  }

  #define ASTORE(e, g) {                                                  \
    float4v av0, av1;                                                     \
    av0[0] = (float)e[0] * invl; av0[1] = (float)e[1] * invl;             \
    av0[2] = (float)e[2] * invl; av0[3] = (float)e[3] * invl;             \
    av1[0] = (float)e[4] * invl; av1[1] = (float)e[5] * invl;             \
    av1[2] = (float)e[6] * invl; av1[3] = (float)e[7] * invl;             \
    *(float4v*)(abase + (g) * 32 + lg * 4) = av0;                         \
    *(float4v*)(abase + (g) * 32 + 16 + lg * 4) = av1;                    \
  }

  for (int h = 0; h < 8; ++h) {
    const int bh = b * 8 + h;
    const int p = h & 1;
    const f16* kfb_nx = (h < 7) ? kfb + 131072 : kfb;

    // Q fragments for this head (L2-hot)
    half8 qf0 = *(const half8*)(qpp + h * 64);
    half8 qf1 = *(const half8*)(qpp + h * 64 + 32);

    float rs = 0.f;
    float4v cacc0 = {}, cacc1 = {}, cacc2 = {}, cacc3 = {};
    half8 e0, e1, e2, e3;

    LOADT(vf, vfb, w * 4 + 0);
    LOADT(kB, kfb, w * 4 + 1);
    BODY(kA, e0, 0);

    LOADT(vf, vfb, w * 4 + 1);
    LOADT(kA, kfb, w * 4 + 2);
    BODY(kB, e1, 1);

    LOADT(vf, vfb, w * 4 + 2);
    LOADT(kB, kfb, w * 4 + 3);
    BODY(kA, e2, 2);

    LOADT(vf, vfb, w * 4 + 3);
    LOADT(kA, kfb_nx, w * 4 + 0);
    BODY(kB, e3, 3);

    // ---- reduction writes to buffer p ----
    rs += __shfl_xor(rs, 16);
    rs += __shfl_xor(rs, 32);
    if (ln < 16) red[p][w][lr] = rs;
    #pragma unroll
    for (int r = 0; r < 4; r++) {
      red2h[p][w][lg * 4 + r][0 * 16 + lr] = (f16)cacc0[r];
      red2h[p][w][lg * 4 + r][1 * 16 + lr] = (f16)cacc1[r];
      red2h[p][w][lg * 4 + r][2 * 16 + lr] = (f16)cacc2[r];
      red2h[p][w][lg * 4 + r][3 * 16 + lr] = (f16)cacc3[r];
    }
    __syncthreads();  // the ONLY barrier this head

    // ---- read ALL sums into registers (buffer p) ----
    float lsum = 0.f;
    #pragma unroll
    for (int ww = 0; ww < 16; ww++) lsum += red[p][ww][lr];
    const float invl = 1.0f / lsum;
    float s16 = 0.f, l2 = 0.f;
    #pragma unroll
    for (int ww = 0; ww < 16; ww++) {
      s16 += (float)red2h[p][ww][w][ln];
      l2 += red[p][ww][w];
    }

    // ---- stores: no trailing barrier; drain under next head's compute ----
    float* abase = attn_out + ((size_t)bh * SS + q_g) * SS + w * 128;
    ASTORE(e0, 0);
    ASTORE(e1, 1);
    ASTORE(e2, 2);
    ASTORE(e3, 3);
    {
      // ctx: wave w handles q-row w; lanes = dv (packed 2-f16 store not
      // needed: single f16 per lane, 64 lanes = 128 B contiguous)
      ctx[((size_t)b * SS + qblk + w) * 512 + h * 64 + ln] = (f16)(s16 / l2);
    }

    kfb = kfb_nx;
    vfb = (h < 7) ? vfb + 131072 : vfb;
  }
  #undef BODY
  #undef ASTORE
}

extern "C" void kernel_launch(void* const* d_in, const int* in_sizes, int n_in,
                              void* d_out, int out_size, void* d_ws, size_t ws_size,
                              hipStream_t stream) {
  const float* inQ   = (const float*)d_in[0];
  const float* inK   = (const float*)d_in[1];
  const float* inV   = (const float*)d_in[2];
  const void*  mask  = d_in[3];
  const float* other = (const float*)d_in[4];
  const float* WQ    = (const float*)d_in[5];
  const float* WK    = (const float*)d_in[6];
  const float* WV    = (const float*)d_in[7];
  const float* WF    = (const float*)d_in[8];

  char* ws = (char*)d_ws;
  size_t off = 0;
  unsigned int* flag = (unsigned int*)(ws + off); off += 256;
  f16* Qp    = (f16*)(ws + off); off += (size_t)MTOK * 512 * 2;
  f16* Kfrag = (f16*)(ws + off); off += (size_t)MTOK * 512 * 2;
  f16* Vfrag = (f16*)(ws + off); off += (size_t)MTOK * 512 * 2;
  f16* ctx   = (f16*)(ws + off); off += (size_t)MTOK * 512 * 2;
  if (ws_size < off) return;

  float* outp  = (float*)d_out;
  float* attnp = outp + (size_t)MTOK * DDIM;

  hipMemsetAsync(flag, 0, 256, stream);
  detect_mask_kernel<<<64, 256, 0, stream>>>((const unsigned int*)mask, flag);

  gemm_qkv<<<dim3(64, 4, 3), 256, 0, stream>>>(inQ, inK, inV, WQ, WK, WV,
                                               Qp, Kfrag, Vfrag);

  attn_fused<<<512, 1024, 0, stream>>>(
      Qp, Kfrag, Vfrag, other, (const unsigned char*)mask, (const int*)mask,
      flag, attnp, ctx);

  gemm_out<<<dim3(64, 4), 256, 0, stream>>>(ctx, WF, outp);
}

// Round 18
// 334.179 us; speedup vs baseline: 1.4753x; 1.0806x over previous
//
#include <hip/hip_runtime.h>

#define BB 4
#define SS 2048
#define DDIM 512
#define HH 8
#define MTOK (BB*SS)   // 8192
#define BHN (BB*HH)    // 32

typedef _Float16 f16;
typedef __attribute__((ext_vector_type(8))) _Float16 half8;
typedef __attribute__((ext_vector_type(4))) _Float16 half4;
typedef __attribute__((ext_vector_type(4))) float float4v;
typedef __attribute__((ext_vector_type(4))) int int4v;

#define SCALE_L2E 0.180336880073616f   // 0.125 * log2(e)
#define L2E 1.44269504088896f
#define EBIAS 4.0f                     // cancels in softmax; f16 overflow headroom
#define MASKVAL -65504.0f              // f16 -max; exp2 -> 0

__device__ __forceinline__ float4v mfma_k32(half8 a, half8 b, float4v c) {
  return __builtin_amdgcn_mfma_f32_16x16x32_f16(a, b, c, 0, 0, 0);
}

__device__ __forceinline__ half8 cvt8(float4v a, float4v b) {
  half8 r;
  r[0] = (f16)a[0]; r[1] = (f16)a[1]; r[2] = (f16)a[2]; r[3] = (f16)a[3];
  r[4] = (f16)b[0]; r[5] = (f16)b[1]; r[6] = (f16)b[2]; r[7] = (f16)b[3];
  return r;
}

// ---------------- mask dtype detection ----------------
__global__ __launch_bounds__(256) void detect_mask_kernel(
    const unsigned int* __restrict__ m, unsigned int* __restrict__ flag) {
  unsigned int v = 0;
  const int base = blockIdx.x * 1024;
  for (int j = threadIdx.x; j < 1024; j += 256)
    if (m[base + j] > 1u) v = 1u;
  if (v) atomicOr(flag, 1u);
}

// ---------------- batched QKV projection (LDS-staged coalesced epilogue) ----------------
// z=0: Qp [tok][512] f16
// z=1: Kfrag[bh][tok>>4][dk>>5][(tok&15)+16*((dk>>3)&3)][dk&7]  (A-frag order)
// z=2: Vfrag[bh][tok>>5][dv>>4][(dv&15)+16*((tok>>2)&3)][((tok>>2)&4)+(tok&3)]
// Epilogue: the 128x128 output tile is staged through LDS (reusing As/Bs) in
// four 32-row chunks so ALL global stores are coalesced 16 B/lane (the old
// path did 64 scalar 2B stores/thread -> 4x the write transactions).
__global__ __launch_bounds__(256) void gemm_qkv(
    const float* __restrict__ inQ, const float* __restrict__ inK,
    const float* __restrict__ inV, const float* __restrict__ WQ,
    const float* __restrict__ WK, const float* __restrict__ WV,
    f16* __restrict__ Qp, f16* __restrict__ Kfrag, f16* __restrict__ Vfrag) {
  __shared__ f16 smem[10240];  // 20 KB: As|Bs in k-loop, tile in epilogue
  f16 (*As)[40] = (f16(*)[40])smem;
  f16 (*Bs)[40] = (f16(*)[40])(smem + 5120);
  const int z = blockIdx.z;
  const float* A = (z == 0) ? inQ : (z == 1) ? inK : inV;
  const float* W = (z == 0) ? WQ : (z == 1) ? WK : WV;
  const int t = threadIdx.x;
  const int bm = blockIdx.x * 128;
  const int bn = blockIdx.y * 128;
  const int w = t >> 6, ln = t & 63;
  const int wr = w >> 1, wc = w & 1;
  const int lr = ln & 15, lg = ln >> 4;
  const int srow = t >> 1, scol = (t & 1) * 16;

  float4v acc[4][4] = {};

  for (int k0 = 0; k0 < 512; k0 += 32) {
    {
      const float* ap = A + (size_t)(bm + srow) * 512 + k0 + scol;
      float4v x0 = *(const float4v*)ap,       x1 = *(const float4v*)(ap + 4);
      float4v x2 = *(const float4v*)(ap + 8), x3 = *(const float4v*)(ap + 12);
      *(half8*)&As[srow][scol]     = cvt8(x0, x1);
      *(half8*)&As[srow][scol + 8] = cvt8(x2, x3);
    }
    {
      const float* wp = W + (size_t)(bn + srow) * 512 + k0 + scol;
      float4v x0 = *(const float4v*)wp,       x1 = *(const float4v*)(wp + 4);
      float4v x2 = *(const float4v*)(wp + 8), x3 = *(const float4v*)(wp + 12);
      *(half8*)&Bs[srow][scol]     = cvt8(x0, x1);
      *(half8*)&Bs[srow][scol + 8] = cvt8(x2, x3);
    }
    __syncthreads();
    half8 af[4], bf[4];
    #pragma unroll
    for (int m = 0; m < 4; m++) af[m] = *(const half8*)&As[wr * 64 + m * 16 + lr][lg * 8];
    #pragma unroll
    for (int n = 0; n < 4; n++) bf[n] = *(const half8*)&Bs[wc * 64 + n * 16 + lr][lg * 8];
    #pragma unroll
    for (int m = 0; m < 4; m++)
      #pragma unroll
      for (int n = 0; n < 4; n++) acc[m][n] = mfma_k32(af[m], bf[n], acc[m][n]);
    __syncthreads();
  }

  // ---- epilogue: 4 chunks of 32 rows through LDS ----
  const int b_ = bm >> 11;          // batch (tile never crosses b boundary)
  const int tokbase = bm & 2047;    // tok of tile row 0
  f16 (*tile)[136] = (f16(*)[136])smem;   // z=0,1: [32][136] (8.7 KB)
  f16 (*tileT)[36] = (f16(*)[36])smem;    // z=2:   [128][36] (9.2 KB)

  #pragma unroll
  for (int cp = 0; cp < 4; cp++) {
    __syncthreads();  // previous chunk (or k-loop) LDS reads complete
    if (wr == (cp >> 1)) {
      #pragma unroll
      for (int mm = 0; mm < 2; mm++) {
        const int m = (cp & 1) * 2 + mm;
        #pragma unroll
        for (int n = 0; n < 4; n++) {
          const int col = wc * 64 + n * 16 + lr;
          #pragma unroll
          for (int r = 0; r < 4; r++) {
            if (z == 2) tileT[col][mm * 16 + lg * 4 + r] = (f16)acc[m][n][r];
            else        tile[mm * 16 + lg * 4 + r][col]  = (f16)acc[m][n][r];
          }
        }
      }
    }
    __syncthreads();  // tile ready

    if (z == 0) {
      const int row = t >> 3, cseg = (t & 7) * 16;
      half8 x0 = *(const half8*)&tile[row][cseg];
      half8 x1 = *(const half8*)&tile[row][cseg + 8];
      f16* dst = Qp + (size_t)(bm + cp * 32 + row) * 512 + bn + cseg;
      *(half8*)dst = x0;
      *(half8*)(dst + 8) = x1;
    } else if (z == 1) {
      const int u = t >> 5, s = t & 31;
      const int tokblk_l = u & 1, head_l = (u >> 1) & 1, dkh = u >> 2;
      const int bh = b_ * 8 + (bn >> 6) + head_l;
      const int tokblk = ((tokbase + cp * 32) >> 4) + tokblk_l;
      f16* ub = Kfrag + (((size_t)bh * 128 + tokblk) * 2 + dkh) * 512;
      #pragma unroll
      for (int e = 0; e < 2; e++) {
        const int fl = 2 * s + e;
        half8 v = *(const half8*)&tile[tokblk_l * 16 + (fl & 15)]
                                      [head_l * 64 + dkh * 32 + (fl >> 4) * 8];
        *(half8*)&ub[fl * 8] = v;
      }
    } else {
      const int u = t >> 5, s = t & 31;
      const int head_l = u & 1, dvq = u >> 1;
      const int bh = b_ * 8 + (bn >> 6) + head_l;
      const int tokblk = (tokbase + cp * 32) >> 5;
      f16* ub = Vfrag + (((size_t)bh * 64 + tokblk) * 4 + dvq) * 512;
      #pragma unroll
      for (int e = 0; e < 2; e++) {
        const int fl = 2 * s + e;
        const int col = head_l * 64 + dvq * 16 + (fl & 15);
        half4 lo = *(const half4*)&tileT[col][(fl >> 4) * 4];
        half4 hi = *(const half4*)&tileT[col][16 + (fl >> 4) * 4];
        half8 v;
        v[0] = lo[0]; v[1] = lo[1]; v[2] = lo[2]; v[3] = lo[3];
        v[4] = hi[0]; v[5] = hi[1]; v[6] = hi[2]; v[7] = hi[3];
        *(half8*)&ub[fl * 8] = v;
      }
    }
  }
}

// ---------------- output GEMM: ctx (f16) x W_fc^T -> fp32 ----------------
__global__ __launch_bounds__(256) void gemm_out(const f16* __restrict__ ctx,
                                                const float* __restrict__ W,
                                                float* __restrict__ Out) {
  __shared__ f16 As[128][40];
  __shared__ f16 Bs[128][40];
  const int t = threadIdx.x;
  const int bm = blockIdx.x * 128;
  const int bn = blockIdx.y * 128;
  const int w = t >> 6, ln = t & 63;
  const int wr = w >> 1, wc = w & 1;
  const int lr = ln & 15, lg = ln >> 4;
  const int srow = t >> 1, scol = (t & 1) * 16;

  float4v acc[4][4] = {};

  for (int k0 = 0; k0 < 512; k0 += 32) {
    {
      const f16* ap = ctx + (size_t)(bm + srow) * 512 + k0 + scol;
      *(half8*)&As[srow][scol]     = *(const half8*)(ap);
      *(half8*)&As[srow][scol + 8] = *(const half8*)(ap + 8);
    }
    {
      const float* wp = W + (size_t)(bn + srow) * 512 + k0 + scol;
      float4v x0 = *(const float4v*)wp,       x1 = *(const float4v*)(wp + 4);
      float4v x2 = *(const float4v*)(wp + 8), x3 = *(const float4v*)(wp + 12);
      *(half8*)&Bs[srow][scol]     = cvt8(x0, x1);
      *(half8*)&Bs[srow][scol + 8] = cvt8(x2, x3);
    }
    __syncthreads();
    half8 af[4], bf[4];
    #pragma unroll
    for (int m = 0; m < 4; m++) af[m] = *(const half8*)&As[wr * 64 + m * 16 + lr][lg * 8];
    #pragma unroll
    for (int n = 0; n < 4; n++) bf[n] = *(const half8*)&Bs[wc * 64 + n * 16 + lr][lg * 8];
    #pragma unroll
    for (int m = 0; m < 4; m++)
      #pragma unroll
      for (int n = 0; n < 4; n++) acc[m][n] = mfma_k32(af[m], bf[n], acc[m][n]);
    __syncthreads();
  }

  #pragma unroll
  for (int m = 0; m < 4; m++) {
    int row = bm + wr * 64 + m * 16 + lg * 4;
    #pragma unroll
    for (int n = 0; n < 4; n++) {
      int col = bn + wc * 64 + n * 16 + lr;
      #pragma unroll
      for (int r = 0; r < 4; r++)
        Out[(size_t)(row + r) * 512 + col] = acc[m][n][r];
    }
  }
}

// ---------------- fused attention: head-sequential, single exp pass (r11) ----------------
// Block = (b, 16 q-rows), 1024 thr = 16 waves; per head (sequential), wave w
// owns k-slice [w*128, w*128+128).  E per wave = 32 f16 (registers) -> ONE
// QK^T + ONE exp per element.  other+mask staged once (66 KB LDS, shared by
// all 8 heads).  PV partials cross-wave reduced via red2 (67 KB LDS).
// 2 barriers per head.  K reg-double-buffered; V issued early in body; next
// head's Q prefetched under the reduce.  b = bid&3 -> K+V (4 MB) L2-resident.
#define LOADT(dst, base, st) {                                  \
    const f16* p_ = (base) + (size_t)(st) * 2048;               \
    dst##0 = *(const half8*)(p_);                               \
    dst##1 = *(const half8*)(p_ + 512);                         \
    dst##2 = *(const half8*)(p_ + 1024);                        \
    dst##3 = *(const half8*)(p_ + 1536); }

__global__ __launch_bounds__(1024) void attn_fused(
    const f16* __restrict__ Qp, const f16* __restrict__ Kfrag,
    const f16* __restrict__ Vfrag, const float* __restrict__ other,
    const unsigned char* __restrict__ mask8, const int* __restrict__ mask32,
    const unsigned int* __restrict__ flag, float* __restrict__ attn_out,
    f16* __restrict__ ctx) {
  __shared__ f16 othm[16][2056];      // masked, log2e-scaled f16  (65.8 KB)
  __shared__ float red[16][16];       // [wave][q] row-sum partials (1 KB)
  __shared__ float red2[16][16][66];  // [wave][q][dv] PV partials (67.6 KB)

  const int t = threadIdx.x;
  const int bid = blockIdx.x;
  const int b = bid & 3;
  const int qblk = (bid >> 2) * 16;
  const int w = t >> 6, ln = t & 63;
  const int lr = ln & 15, lg = ln >> 4;
  const bool use8 = (*flag) != 0;

  // ---- stage other+mask once: thread -> (q = t>>6, 32 k at (t&63)*32) ----
  {
    const int q = t >> 6, k0 = (t & 63) * 32;
    const size_t base = ((size_t)b * SS + qblk + q) * SS + k0;
    const float* op = other + base;
    if (use8) {
      const unsigned char* mp = mask8 + base;
      #pragma unroll
      for (int g = 0; g < 4; g++) {
        unsigned int mw0 = *(const unsigned int*)(mp + g * 8);
        unsigned int mw1 = *(const unsigned int*)(mp + g * 8 + 4);
        float4v o0 = *(const float4v*)(op + g * 8);
        float4v o1 = *(const float4v*)(op + g * 8 + 4);
        float4v r0, r1;
        #pragma unroll
        for (int r = 0; r < 4; r++) {
          r0[r] = ((mw0 >> (8 * r)) & 0xffu) ? MASKVAL : fmaf(o0[r], L2E, -EBIAS);
          r1[r] = ((mw1 >> (8 * r)) & 0xffu) ? MASKVAL : fmaf(o1[r], L2E, -EBIAS);
        }
        *(half8*)&othm[q][k0 + g * 8] = cvt8(r0, r1);
      }
    } else {
      const int* mp = mask32 + base;
      #pragma unroll
      for (int g = 0; g < 4; g++) {
        int4v m0 = *(const int4v*)(mp + g * 8);
        int4v m1 = *(const int4v*)(mp + g * 8 + 4);
        float4v o0 = *(const float4v*)(op + g * 8);
        float4v o1 = *(const float4v*)(op + g * 8 + 4);
        float4v r0, r1;
        #pragma unroll
        for (int r = 0; r < 4; r++) {
          r0[r] = m0[r] ? MASKVAL : fmaf(o0[r], L2E, -EBIAS);
          r1[r] = m1[r] ? MASKVAL : fmaf(o1[r], L2E, -EBIAS);
        }
        *(half8*)&othm[q][k0 + g * 8] = cvt8(r0, r1);
      }
    }
  }
  __syncthreads();

  const int q_g = qblk + lr;
  const f16* kfb = Kfrag + (size_t)(b * 8) * 131072 + ln * 8;
  const f16* vfb = Vfrag + (size_t)(b * 8) * 131072 + ln * 8;
  const f16* qpp = Qp + ((size_t)b * SS + q_g) * 512 + lg * 8;

  half8 qf0 = *(const half8*)(qpp);
  half8 qf1 = *(const half8*)(qpp + 32);

  half8 kA0, kA1, kA2, kA3, kB0, kB1, kB2, kB3;
  half8 vf0, vf1, vf2, vf3;

  LOADT(kA, kfb, w * 4 + 0);

  #define BODY(kf, edst, g) {                                             \
    float4v s0 = {}, s1 = {};                                             \
    s0 = mfma_k32(kf##0, qf0, s0);                                        \
    s0 = mfma_k32(kf##1, qf1, s0);                                        \
    s1 = mfma_k32(kf##2, qf0, s1);                                        \
    s1 = mfma_k32(kf##3, qf1, s1);                                        \
    const int kbase = w * 128 + (g) * 32;                                 \
    const half4 o40 = *(const half4*)&othm[lr][kbase + lg * 4];           \
    const half4 o41 = *(const half4*)&othm[lr][kbase + 16 + lg * 4];      \
    float4v ev0, ev1;                                                     \
    _Pragma("unroll")                                                     \
    for (int r = 0; r < 4; r++) {                                         \
      ev0[r] = exp2f(fmaf(s0[r], SCALE_L2E, (float)o40[r]));              \
      ev1[r] = exp2f(fmaf(s1[r], SCALE_L2E, (float)o41[r]));              \
    }                                                                     \
    rs += (ev0[0] + ev0[1]) + (ev0[2] + ev0[3]) +                         \
          (ev1[0] + ev1[1]) + (ev1[2] + ev1[3]);                          \
    edst = cvt8(ev0, ev1);                                                \
    cacc0 = mfma_k32(edst, vf0, cacc0);                                   \
    cacc1 = mfma_k32(edst, vf1, cacc1);                                   \
    cacc2 = mfma_k32(edst, vf2, cacc2);                                   \
    cacc3 = mfma_k32(edst, vf3, cacc3);                                   \
  }

  #define ASTORE(e, g) {                                                  \
    float4v av0, av1;                                                     \
    av0[0] = (float)e[0] * invl; av0[1] = (float)e[1] * invl;             \
    av0[2] = (float)e[2] * invl; av0[3] = (float)e[3] * invl;             \
    av1[0] = (float)e[4] * invl; av1[1] = (float)e[5] * invl;             \
    av1[2] = (float)e[6] * invl; av1[3] = (float)e[7] * invl;             \
    *(float4v*)(abase + (g) * 32 + lg * 4) = av0;                         \
    *(float4v*)(abase + (g) * 32 + 16 + lg * 4) = av1;                    \
  }

  for (int h = 0; h < 8; ++h) {
    const int bh = b * 8 + h;
    const f16* kfb_nx = (h < 7) ? kfb + 131072 : kfb;

    float rs = 0.f;
    float4v cacc0 = {}, cacc1 = {}, cacc2 = {}, cacc3 = {};
    half8 e0, e1, e2, e3;

    LOADT(vf, vfb, w * 4 + 0);
    LOADT(kB, kfb, w * 4 + 1);
    BODY(kA, e0, 0);

    LOADT(vf, vfb, w * 4 + 1);
    LOADT(kA, kfb, w * 4 + 2);
    BODY(kB, e1, 1);

    LOADT(vf, vfb, w * 4 + 2);
    LOADT(kB, kfb, w * 4 + 3);
    BODY(kA, e2, 2);

    LOADT(vf, vfb, w * 4 + 3);
    LOADT(kA, kfb_nx, w * 4 + 0);
    BODY(kB, e3, 3);

    // prefetch next head's Q (consumed after the barriers)
    const int hn = (h < 7) ? h + 1 : 7;
    half8 qn0 = *(const half8*)(qpp + hn * 64);
    half8 qn1 = *(const half8*)(qpp + hn * 64 + 32);

    // ---- cross-wave reductions ----
    rs += __shfl_xor(rs, 16);
    rs += __shfl_xor(rs, 32);
    if (ln < 16) red[w][lr] = rs;
    #pragma unroll
    for (int r = 0; r < 4; r++) {
      red2[w][lg * 4 + r][0 * 16 + lr] = cacc0[r];
      red2[w][lg * 4 + r][1 * 16 + lr] = cacc1[r];
      red2[w][lg * 4 + r][2 * 16 + lr] = cacc2[r];
      red2[w][lg * 4 + r][3 * 16 + lr] = cacc3[r];
    }
    __syncthreads();

    float lsum = 0.f;
    #pragma unroll
    for (int ww = 0; ww < 16; ww++) lsum += red[ww][lr];
    const float invl = 1.0f / lsum;

    float* abase = attn_out + ((size_t)bh * SS + q_g) * SS + w * 128;
    ASTORE(e0, 0);
    ASTORE(e1, 1);
    ASTORE(e2, 2);
    ASTORE(e3, 3);

    // ctx: wave w handles q-row w; lanes = dv
    {
      float s16 = 0.f, l2 = 0.f;
      #pragma unroll
      for (int ww = 0; ww < 16; ww++) {
        s16 += red2[ww][w][ln];
        l2 += red[ww][w];
      }
      ctx[((size_t)b * SS + qblk + w) * 512 + h * 64 + ln] = (f16)(s16 / l2);
    }
    __syncthreads();

    qf0 = qn0;
    qf1 = qn1;
    kfb = kfb_nx;
    vfb = (h < 7) ? vfb + 131072 : vfb;
  }
  #undef BODY
  #undef ASTORE
}

extern "C" void kernel_launch(void* const* d_in, const int* in_sizes, int n_in,
                              void* d_out, int out_size, void* d_ws, size_t ws_size,
                              hipStream_t stream) {
  const float* inQ   = (const float*)d_in[0];
  const float* inK   = (const float*)d_in[1];
  const float* inV   = (const float*)d_in[2];
  const void*  mask  = d_in[3];
  const float* other = (const float*)d_in[4];
  const float* WQ    = (const float*)d_in[5];
  const float* WK    = (const float*)d_in[6];
  const float* WV    = (const float*)d_in[7];
  const float* WF    = (const float*)d_in[8];

  char* ws = (char*)d_ws;
  size_t off = 0;
  unsigned int* flag = (unsigned int*)(ws + off); off += 256;
  f16* Qp    = (f16*)(ws + off); off += (size_t)MTOK * 512 * 2;
  f16* Kfrag = (f16*)(ws + off); off += (size_t)MTOK * 512 * 2;
  f16* Vfrag = (f16*)(ws + off); off += (size_t)MTOK * 512 * 2;
  f16* ctx   = (f16*)(ws + off); off += (size_t)MTOK * 512 * 2;
  if (ws_size < off) return;

  float* outp  = (float*)d_out;
  float* attnp = outp + (size_t)MTOK * DDIM;

  hipMemsetAsync(flag, 0, 256, stream);
  detect_mask_kernel<<<64, 256, 0, stream>>>((const unsigned int*)mask, flag);

  gemm_qkv<<<dim3(64, 4, 3), 256, 0, stream>>>(inQ, inK, inV, WQ, WK, WV,
                                               Qp, Kfrag, Vfrag);

  attn_fused<<<512, 1024, 0, stream>>>(
      Qp, Kfrag, Vfrag, other, (const unsigned char*)mask, (const int*)mask,
      flag, attnp, ctx);

  gemm_out<<<dim3(64, 4), 256, 0, stream>>>(ctx, WF, outp);
}